// Round 4
// baseline (14024.886 us; speedup 1.0000x reference)
//
#include <hip/hip_runtime.h>
#include <stdint.h>

// Problem constants
#define B_ 32
#define T_ 2048
#define D_ 512
#define N_ 512
#define NG 2048   // 4 gates * N

typedef _Float16 f16;
typedef _Float16 half2v __attribute__((ext_vector_type(2)));
typedef _Float16 half8  __attribute__((ext_vector_type(8)));
typedef float    float4v __attribute__((ext_vector_type(4)));
typedef unsigned long long u64;

union U32H2 { unsigned u; half2v h; };
union U4H8  { uint4 u; half8 h; };
union H16U  { f16 h; unsigned short s; };

static __device__ __forceinline__ float fast_sigmoid(float x) {
    return __builtin_amdgcn_rcpf(1.f + __expf(-x));
}
static __device__ __forceinline__ float fast_tanh(float x) {
    // 1 - 2/(1+e^{2x}): correct limits at +/-inf, no clamp needed
    return 1.f - 2.f * __builtin_amdgcn_rcpf(1.f + __expf(2.f * x));
}

// ---------------- prep: cast x (f32) -> f16 ----------------
__global__ void prep_cast(const float* __restrict__ x, f16* __restrict__ x16) {
    long i = ((long)blockIdx.x * 256 + threadIdx.x) * 4;
    float4 v = *(const float4*)(x + i);
    union { f16 h[4]; uint2 u; } pk;
    pk.h[0] = (f16)v.x; pk.h[1] = (f16)v.y; pk.h[2] = (f16)v.z; pk.h[3] = (f16)v.w;
    *(uint2*)(x16 + i) = pk.u;
}

// ---------------- prep: transpose+cast weights, biases ----------------
__global__ void prep_w(const float* __restrict__ Wi, const float* __restrict__ Ui,
                       const float* __restrict__ Wf, const float* __restrict__ Uf,
                       const float* __restrict__ Wg, const float* __restrict__ Ug,
                       const float* __restrict__ Wc, const float* __restrict__ Uc,
                       const float* __restrict__ Wo,
                       const float* __restrict__ bi, const float* __restrict__ bff,
                       const float* __restrict__ bg, const float* __restrict__ bc,
                       f16* __restrict__ wt, f16* __restrict__ ut,
                       f16* __restrict__ wot, float* __restrict__ bias)
{
    const int y = blockIdx.y;
    const int e = blockIdx.x * 256 + threadIdx.x;   // 0..262143
    if (y < 4) {
        const float* src = (y == 0) ? Wi : (y == 1) ? Wf : (y == 2) ? Wg : Wc;
        int col = e >> 9, d = e & 511;
        wt[(long)y * 512 * 512 + e] = (f16)src[(long)d * 512 + col];   // wt[(g*512+col)][d]
    } else if (y < 8) {
        const float* src = (y == 4) ? Ui : (y == 5) ? Uf : (y == 6) ? Ug : Uc;
        int col = e >> 9, d = e & 511;
        ut[(long)(y - 4) * 512 * 512 + e] = (f16)src[(long)d * 512 + col];
    } else if (y == 8) {
        int col = e >> 9, d = e & 511;
        wot[e] = (f16)Wo[(long)d * 512 + col];
    } else {
        if (e < 2048) {
            const float* bsrc = (e < 512) ? bi : (e < 1024) ? bff : (e < 1536) ? bg : bc;
            bias[e] = bsrc[e & 511];
        }
    }
}

// ---------------- phase 1: xpre[b][t][2048] = x @ [Wi|Wf|Wg|Wc] + bias (f16 out) ----------------
__launch_bounds__(256)
__global__ void gemm_xw(const f16* __restrict__ A, const f16* __restrict__ Bt,
                        const float* __restrict__ bias, f16* __restrict__ C)
{
    __shared__ f16 sA[128 * 32];
    __shared__ f16 sB[128 * 32];
    const int tid = threadIdx.x;
    const int m0 = blockIdx.y * 128;
    const int n0 = blockIdx.x * 128;
    const int wave = tid >> 6, lane = tid & 63;
    const int wm = wave >> 1, wn = wave & 1;
    const int lrow = lane & 15, quad = lane >> 4;

    float4v acc[4][4];
#pragma unroll
    for (int i = 0; i < 4; i++)
#pragma unroll
        for (int j = 0; j < 4; j++) acc[i][j] = (float4v){0.f, 0.f, 0.f, 0.f};

    const int srow = tid >> 2;        // 0..63
    const int sk8 = (tid & 3) * 8;    // 0,8,16,24

    for (int k0 = 0; k0 < 512; k0 += 32) {
#pragma unroll
        for (int rr = 0; rr < 128; rr += 64) {
            const int row = rr + srow;
            *(uint4*)&sA[row * 32 + sk8] = *(const uint4*)&A[(long)(m0 + row) * 512 + k0 + sk8];
            *(uint4*)&sB[row * 32 + sk8] = *(const uint4*)&Bt[(long)(n0 + row) * 512 + k0 + sk8];
        }
        __syncthreads();
        half8 af[4], bf[4];
#pragma unroll
        for (int mi = 0; mi < 4; mi++)
            af[mi] = *(half8*)&sA[(wm * 64 + mi * 16 + lrow) * 32 + quad * 8];
#pragma unroll
        for (int ni = 0; ni < 4; ni++)
            bf[ni] = *(half8*)&sB[(wn * 64 + ni * 16 + lrow) * 32 + quad * 8];
#pragma unroll
        for (int mi = 0; mi < 4; mi++)
#pragma unroll
            for (int ni = 0; ni < 4; ni++)
                acc[mi][ni] = __builtin_amdgcn_mfma_f32_16x16x32_f16(af[mi], bf[ni], acc[mi][ni], 0, 0, 0);
        __syncthreads();
    }
#pragma unroll
    for (int mi = 0; mi < 4; mi++)
#pragma unroll
        for (int ni = 0; ni < 4; ni++)
#pragma unroll
            for (int r = 0; r < 4; r++) {
                int m = m0 + wm * 64 + mi * 16 + quad * 4 + r;
                int n = n0 + wn * 64 + ni * 16 + lrow;
                C[(long)m * NG + n] = (f16)(acc[mi][ni][r] + bias[n]);
            }
}

// ---------------- phase 3: out[b][t][n] = relu(hs @ Wo + bo) (f32 out, row remap) ----------------
__launch_bounds__(256)
__global__ void gemm_hw(const f16* __restrict__ A, const f16* __restrict__ Bt,
                        const float* __restrict__ bias, float* __restrict__ out)
{
    __shared__ f16 sA[128 * 32];
    __shared__ f16 sB[128 * 32];
    const int tid = threadIdx.x;
    const int m0 = blockIdx.y * 128;
    const int n0 = blockIdx.x * 128;
    const int wave = tid >> 6, lane = tid & 63;
    const int wm = wave >> 1, wn = wave & 1;
    const int lrow = lane & 15, quad = lane >> 4;

    float4v acc[4][4];
#pragma unroll
    for (int i = 0; i < 4; i++)
#pragma unroll
        for (int j = 0; j < 4; j++) acc[i][j] = (float4v){0.f, 0.f, 0.f, 0.f};

    const int srow = tid >> 2;
    const int sk8 = (tid & 3) * 8;

    for (int k0 = 0; k0 < 512; k0 += 32) {
#pragma unroll
        for (int rr = 0; rr < 128; rr += 64) {
            const int row = rr + srow;
            *(uint4*)&sA[row * 32 + sk8] = *(const uint4*)&A[(long)(m0 + row) * 512 + k0 + sk8];
            *(uint4*)&sB[row * 32 + sk8] = *(const uint4*)&Bt[(long)(n0 + row) * 512 + k0 + sk8];
        }
        __syncthreads();
        half8 af[4], bf[4];
#pragma unroll
        for (int mi = 0; mi < 4; mi++)
            af[mi] = *(half8*)&sA[(wm * 64 + mi * 16 + lrow) * 32 + quad * 8];
#pragma unroll
        for (int ni = 0; ni < 4; ni++)
            bf[ni] = *(half8*)&sB[(wn * 64 + ni * 16 + lrow) * 32 + quad * 8];
#pragma unroll
        for (int mi = 0; mi < 4; mi++)
#pragma unroll
            for (int ni = 0; ni < 4; ni++)
                acc[mi][ni] = __builtin_amdgcn_mfma_f32_16x16x32_f16(af[mi], bf[ni], acc[mi][ni], 0, 0, 0);
        __syncthreads();
    }
#pragma unroll
    for (int mi = 0; mi < 4; mi++)
#pragma unroll
        for (int ni = 0; ni < 4; ni++)
#pragma unroll
            for (int r = 0; r < 4; r++) {
                int m = m0 + wm * 64 + mi * 16 + quad * 4 + r;   // m = t*B + b
                int n = n0 + wn * 64 + ni * 16 + lrow;
                float v = acc[mi][ni][r] + bias[n];
                v = fmaxf(v, 0.f);
                int t = m >> 5, b = m & 31;
                out[(long)b * (T_ * (long)N_) + (long)t * N_ + n] = v;
            }
}

// ---------------- phase 2: the recurrence (16-batch MFMA) ----------------
// 2 groups of 16 batches; group g served by 8 blocks (slices of 64 n-cols x
// 4 gates). Launch 64 blocks; only (blk&7)<2 run -> real blocks of a group are
// congruent mod 8 => same XCD (L2-local tagged-slot ring).
// MFMA M-dim carries 16 BATCHES: A = h of 16 batches (from LDS hbuf, XOR-
// swizzled so the A-frag ds_read_b128 is ~2-way), B = persistent U columns in
// registers (wave = gate; 4 tiles x 16 K-steps). One 16x16x32 MFMA computes
// 16 batches x 16 gate-cols -> 16x less matrix-pipe work than the
// one-batch-broadcast design, and the store->poll handoff is paid once per
// step for 16 batches instead of once per batch.
// 8 independent accumulator chains (tile x ks-parity) keep the MFMA pipe fed
// (R3's 4-chain version stalled on MFMA latency).
// Comm protocol unchanged: tagged u64 per h-pair, relaxed agent-scope atomics,
// parity double-buffer. Producer overwrites a parity-p slot (tag t+2 over t)
// only after its block observed tag t+1 on all polled slots, which requires
// every peer block to have passed the barrier following its tag-t reads.
__launch_bounds__(256, 1)
__global__ void lstm_rec(const f16* __restrict__ Ut,      // [2048 cols][512 rows] f16
                         const f16* __restrict__ xpre,    // [B][T][2048] f16
                         u64* __restrict__ hg64,          // [2][32][256] tagged h pairs
                         unsigned* __restrict__ hs32,     // [T][B][256] u32 (packed f16x2)
                         int unused)
{
    if ((blockIdx.x & 7) >= 2) return;    // dummy blocks for XCD placement
    const int group = blockIdx.x & 7;     // 0 or 1 (16 batches each)
    const int slice = blockIdx.x >> 3;    // 0..7 (64 n-cols each)
    const int n0 = slice * 64;

    const int tid  = threadIdx.x;         // 0..255
    const int g    = tid >> 6;            // wave = gate 0..3
    const int lane = tid & 63;
    const int quad = lane >> 4;           // 0..3
    const int lcol = lane & 15;           // MFMA col (n) / row (batch) index

    __shared__ __align__(16) unsigned hbuf[4096];     // h: [16 b][256 dw], XOR-swizzled
    __shared__ float prelds[4224];                    // [4 g][16 b][66 (64 n + pad)]

    // ---- persistent B-fragments: this wave's gate, 4 n-tiles x 16 ks ----
    half8 bf[4][16];
#pragma unroll
    for (int nt = 0; nt < 4; nt++) {
        const f16* bp = Ut + (long)(g * 512 + n0 + nt * 16 + lcol) * 512 + quad * 8;
#pragma unroll
        for (int ks = 0; ks < 16; ks++)
            bf[nt][ks] = *(const half8*)(bp + ks * 32);
    }

    // zero h_{-1}
#pragma unroll
    for (int i = 0; i < 16; i++) hbuf[tid * 16 + i] = 0u;

    // gate-thread identity: batch b, pair-slot tau; covers np in {tau, tau+16}
    const int b   = tid >> 4;             // 0..15
    const int tau = tid & 15;
    const int bglobal = group * 16 + b;
    const int sw = (b & 7) << 2;          // hbuf write swizzle for this thread

    // c-state: 4 columns (2 np-pairs x 2 cols)
    float cs00 = 0.f, cs01 = 0.f, cs10 = 0.f, cs11 = 0.f;

    // xpre addressing (u32 = packed pair): idx = t*1024 + g*256 + np
    const unsigned* xq = (const unsigned*)(xpre + (long)bglobal * T_ * NG + n0);
    unsigned xc[8], xn[8];
#pragma unroll
    for (int gg = 0; gg < 4; gg++)
#pragma unroll
        for (int j = 0; j < 2; j++)
            xc[gg * 2 + j] = xq[gg * 256 + tau + j * 16];   // t = 0

    __syncthreads();   // prologue full sync (one-time vmcnt drain is fine)

#pragma unroll 1
    for (int t = 0; t < T_; ++t) {
        // ---- P0: poll h_{t-1} (16 tagged slots per thread = whole group) ----
        if (t > 0) {
            const u64* base = hg64 + (size_t)(t & 1) * 8192 + (size_t)group * 4096 + (size_t)tid * 16;
            const unsigned tag = (unsigned)t;
            u64 v[16];
#pragma unroll
            for (int i = 0; i < 16; i++)
                v[i] = __hip_atomic_load(base + i, __ATOMIC_RELAXED, __HIP_MEMORY_SCOPE_AGENT);
#pragma unroll
            for (int i = 0; i < 16; i++)
                while ((unsigned)(v[i] >> 32) != tag)
                    v[i] = __hip_atomic_load(base + i, __ATOMIC_RELAXED, __HIP_MEMORY_SCOPE_AGENT);
            __builtin_amdgcn_sched_barrier(0);   // keep prefetch below the poll waits

            // xpre prefetch for t+1 (drained by NEXT step's poll, ~1 step away)
            {
                const long tn = (t + 1 < T_) ? (t + 1) : t;
#pragma unroll
                for (int gg = 0; gg < 4; gg++)
#pragma unroll
                    for (int j = 0; j < 2; j++)
                        xn[gg * 2 + j] = xq[tn * 1024 + gg * 256 + tau + j * 16];
            }

            // write h into swizzled hbuf: pairs p0..p0+15 of batch b
            const int p0 = tau * 16;
#pragma unroll
            for (int c = 0; c < 4; c++) {
                uint4 d;
                d.x = (unsigned)v[c * 4 + 0];
                d.y = (unsigned)v[c * 4 + 1];
                d.z = (unsigned)v[c * 4 + 2];
                d.w = (unsigned)v[c * 4 + 3];
                *(uint4*)&hbuf[b * 256 + ((p0 + c * 4) ^ sw)] = d;
            }
        } else {
            // t=0: hbuf already zero; still prefetch t=1
#pragma unroll
            for (int gg = 0; gg < 4; gg++)
#pragma unroll
                for (int j = 0; j < 2; j++)
                    xn[gg * 2 + j] = xq[1024 + gg * 256 + tau + j * 16];
        }

        asm volatile("s_waitcnt lgkmcnt(0)" ::: "memory");
        __builtin_amdgcn_s_barrier();
        __builtin_amdgcn_sched_barrier(0);

        // ---- P1: MFMA  (A = 16 batches' h, B = U frags) ----
        uint4 av[16];
        {
            const int swb = (lcol & 7) << 2;     // batch = lcol
#pragma unroll
            for (int ks = 0; ks < 16; ks++)
                av[ks] = *(const uint4*)&hbuf[lcol * 256 + (((ks * 16 + quad * 4)) ^ swb)];
        }
        float4v ae[4], ao[4];
#pragma unroll
        for (int nt = 0; nt < 4; nt++) {
            ae[nt] = (float4v){0.f, 0.f, 0.f, 0.f};
            ao[nt] = (float4v){0.f, 0.f, 0.f, 0.f};
        }
#pragma unroll
        for (int ks = 0; ks < 16; ks++) {
            U4H8 a; a.u = av[ks];
            if (ks & 1) {
#pragma unroll
                for (int nt = 0; nt < 4; nt++)
                    ao[nt] = __builtin_amdgcn_mfma_f32_16x16x32_f16(a.h, bf[nt][ks], ao[nt], 0, 0, 0);
            } else {
#pragma unroll
                for (int nt = 0; nt < 4; nt++)
                    ae[nt] = __builtin_amdgcn_mfma_f32_16x16x32_f16(a.h, bf[nt][ks], ae[nt], 0, 0, 0);
            }
        }

        // ---- P2: write pre-acts to prelds: [g][b=quad*4+r][n=nt*16+lcol] ----
#pragma unroll
        for (int nt = 0; nt < 4; nt++) {
            float4v s;
#pragma unroll
            for (int r = 0; r < 4; r++) s[r] = ae[nt][r] + ao[nt][r];
#pragma unroll
            for (int r = 0; r < 4; r++)
                prelds[g * 1056 + (quad * 4 + r) * 66 + nt * 16 + lcol] = s[r];
        }

        asm volatile("s_waitcnt lgkmcnt(0)" ::: "memory");
        __builtin_amdgcn_s_barrier();
        __builtin_amdgcn_sched_barrier(0);

        // ---- P3: gates (all 256 threads; thread = (b, tau); 2 np-pairs) ----
#pragma unroll
        for (int j = 0; j < 2; j++) {
            const int np = tau + j * 16;
            const float* pb = prelds + b * 66 + 2 * np;
            float2 Pi = *(const float2*)(pb);
            float2 Pf = *(const float2*)(pb + 1056);
            float2 Pg = *(const float2*)(pb + 2112);
            float2 Pc = *(const float2*)(pb + 3168);
            U32H2 xi, xf, xg, xcc;
            xi.u = xc[0 * 2 + j]; xf.u = xc[1 * 2 + j];
            xg.u = xc[2 * 2 + j]; xcc.u = xc[3 * 2 + j];

            float gi0 = fast_sigmoid(Pi.x + (float)xi.h[0]);
            float gi1 = fast_sigmoid(Pi.y + (float)xi.h[1]);
            float gf0 = fast_sigmoid(Pf.x + (float)xf.h[0]);
            float gf1 = fast_sigmoid(Pf.y + (float)xf.h[1]);
            float gg0 = fast_sigmoid(Pg.x + (float)xg.h[0]);
            float gg1 = fast_sigmoid(Pg.y + (float)xg.h[1]);
            float ct0 = fast_tanh(Pc.x + (float)xcc.h[0]);
            float ct1 = fast_tanh(Pc.y + (float)xcc.h[1]);

            float c0 = (j == 0) ? cs00 : cs10;
            float c1 = (j == 0) ? cs01 : cs11;
            c0 = gf0 * c0 + gi0 * ct0;
            c1 = gf1 * c1 + gi1 * ct1;
            if (j == 0) { cs00 = c0; cs01 = c1; } else { cs10 = c0; cs11 = c1; }

            float h0 = gg0 * fast_tanh(c0);
            float h1 = gg1 * fast_tanh(c1);

            H16U u0, u1; u0.h = (f16)h0; u1.h = (f16)h1;
            unsigned pk = (unsigned)u0.s | ((unsigned)u1.s << 16);
            u64 pv = ((u64)(unsigned)(t + 1) << 32) | (u64)pk;
            const int pair = slice * 32 + np;
            __hip_atomic_store(hg64 + (size_t)((t + 1) & 1) * 8192 + (size_t)bglobal * 256 + pair,
                               pv, __ATOMIC_RELAXED, __HIP_MEMORY_SCOPE_AGENT);
            // history for gemm_hw (not on critical path)
            hs32[((long)t * B_ + bglobal) * 256 + pair] = pk;
        }

        // rotate xpre pipeline registers
#pragma unroll
        for (int k = 0; k < 8; k++) xc[k] = xn[k];
        // no trailing barrier: next poll + barrier provide ordering
    }
}

// ---------------- launch ----------------
extern "C" void kernel_launch(void* const* d_in, const int* in_sizes, int n_in,
                              void* d_out, int out_size, void* d_ws, size_t ws_size,
                              hipStream_t stream)
{
    const float* x  = (const float*)d_in[0];
    const float* Wi = (const float*)d_in[1];
    const float* Ui = (const float*)d_in[2];
    const float* Wf = (const float*)d_in[3];
    const float* Uf = (const float*)d_in[4];
    const float* Wg = (const float*)d_in[5];
    const float* Ug = (const float*)d_in[6];
    const float* Wc = (const float*)d_in[7];
    const float* Uc = (const float*)d_in[8];
    const float* Wo = (const float*)d_in[9];
    const float* bi = (const float*)d_in[10];
    const float* bf = (const float*)d_in[11];
    const float* bg = (const float*)d_in[12];
    const float* bc = (const float*)d_in[13];
    const float* bo = (const float*)d_in[14];

    char* ws = (char*)d_ws;
    f16*      x16   = (f16*)(ws + 0L);            // 64 MB
    f16*      xpre  = (f16*)(ws + 67108864L);     // 256 MB
    f16*      hs    = (f16*)(ws + 335544320L);    // 64 MB
    f16*      wt    = (f16*)(ws + 402653184L);    // 2 MB
    f16*      ut    = (f16*)(ws + 404750336L);    // 2 MB
    f16*      wot   = (f16*)(ws + 406847488L);    // 0.5 MB
    float*    bias  = (float*)(ws + 407371776L);  // 8 KB
    u64*      hg64  = (u64*)(ws + 407379968L);    // 128 KB tagged h exchange
    // hg64 is re-poisoned to 0xAA each call -> tag 0xAAAAAAAA never matches a
    // real t in [1,2048], so stale data cannot satisfy a poll.

    prep_cast<<<dim3(32768), dim3(256), 0, stream>>>(x, x16);
    prep_w<<<dim3(1024, 10), dim3(256), 0, stream>>>(Wi, Ui, Wf, Uf, Wg, Ug, Wc, Uc, Wo,
                                                     bi, bf, bg, bc, wt, ut, wot, bias);
    gemm_xw<<<dim3(16, 512), dim3(256), 0, stream>>>(x16, wt, bias, xpre);
    lstm_rec<<<dim3(64), dim3(256), 0, stream>>>(ut, xpre, hg64, (unsigned*)hs, 0);
    gemm_hw<<<dim3(4, 512), dim3(256), 0, stream>>>(hs, wot, bo, (float*)d_out);
}

// Round 5
// 11608.310 us; speedup vs baseline: 1.2082x; 1.2082x over previous
//
#include <hip/hip_runtime.h>
#include <stdint.h>

// Problem constants
#define B_ 32
#define T_ 2048
#define D_ 512
#define N_ 512
#define NG 2048   // 4 gates * N

typedef _Float16 f16;
typedef _Float16 half2v __attribute__((ext_vector_type(2)));
typedef _Float16 half8  __attribute__((ext_vector_type(8)));
typedef float    float4v __attribute__((ext_vector_type(4)));
typedef unsigned long long u64;

union U32H2 { unsigned u; half2v h; };
union U4H8  { uint4 u; half8 h; };
union H16U  { f16 h; unsigned short s; };

static __device__ __forceinline__ float fast_sigmoid(float x) {
    return __builtin_amdgcn_rcpf(1.f + __expf(-x));
}
static __device__ __forceinline__ float fast_tanh(float x) {
    // 1 - 2/(1+e^{2x}): correct limits at +/-inf, no clamp needed
    return 1.f - 2.f * __builtin_amdgcn_rcpf(1.f + __expf(2.f * x));
}

// ---------------- prep: cast x (f32) -> f16 ----------------
__global__ void prep_cast(const float* __restrict__ x, f16* __restrict__ x16) {
    long i = ((long)blockIdx.x * 256 + threadIdx.x) * 4;
    float4 v = *(const float4*)(x + i);
    union { f16 h[4]; uint2 u; } pk;
    pk.h[0] = (f16)v.x; pk.h[1] = (f16)v.y; pk.h[2] = (f16)v.z; pk.h[3] = (f16)v.w;
    *(uint2*)(x16 + i) = pk.u;
}

// ---------------- prep: transpose+cast weights, biases ----------------
__global__ void prep_w(const float* __restrict__ Wi, const float* __restrict__ Ui,
                       const float* __restrict__ Wf, const float* __restrict__ Uf,
                       const float* __restrict__ Wg, const float* __restrict__ Ug,
                       const float* __restrict__ Wc, const float* __restrict__ Uc,
                       const float* __restrict__ Wo,
                       const float* __restrict__ bi, const float* __restrict__ bff,
                       const float* __restrict__ bg, const float* __restrict__ bc,
                       f16* __restrict__ wt, f16* __restrict__ ut,
                       f16* __restrict__ wot, float* __restrict__ bias)
{
    const int y = blockIdx.y;
    const int e = blockIdx.x * 256 + threadIdx.x;   // 0..262143
    if (y < 4) {
        const float* src = (y == 0) ? Wi : (y == 1) ? Wf : (y == 2) ? Wg : Wc;
        int col = e >> 9, d = e & 511;
        wt[(long)y * 512 * 512 + e] = (f16)src[(long)d * 512 + col];   // wt[(g*512+col)][d]
    } else if (y < 8) {
        const float* src = (y == 4) ? Ui : (y == 5) ? Uf : (y == 6) ? Ug : Uc;
        int col = e >> 9, d = e & 511;
        ut[(long)(y - 4) * 512 * 512 + e] = (f16)src[(long)d * 512 + col];
    } else if (y == 8) {
        int col = e >> 9, d = e & 511;
        wot[e] = (f16)Wo[(long)d * 512 + col];
    } else {
        if (e < 2048) {
            const float* bsrc = (e < 512) ? bi : (e < 1024) ? bff : (e < 1536) ? bg : bc;
            bias[e] = bsrc[e & 511];
        }
    }
}

// ---------------- phase 1: xpre[b][t][2048] = x @ [Wi|Wf|Wg|Wc] + bias (f16 out) ----------------
__launch_bounds__(256)
__global__ void gemm_xw(const f16* __restrict__ A, const f16* __restrict__ Bt,
                        const float* __restrict__ bias, f16* __restrict__ C)
{
    __shared__ f16 sA[128 * 32];
    __shared__ f16 sB[128 * 32];
    const int tid = threadIdx.x;
    const int m0 = blockIdx.y * 128;
    const int n0 = blockIdx.x * 128;
    const int wave = tid >> 6, lane = tid & 63;
    const int wm = wave >> 1, wn = wave & 1;
    const int lrow = lane & 15, quad = lane >> 4;

    float4v acc[4][4];
#pragma unroll
    for (int i = 0; i < 4; i++)
#pragma unroll
        for (int j = 0; j < 4; j++) acc[i][j] = (float4v){0.f, 0.f, 0.f, 0.f};

    const int srow = tid >> 2;        // 0..63
    const int sk8 = (tid & 3) * 8;    // 0,8,16,24

    for (int k0 = 0; k0 < 512; k0 += 32) {
#pragma unroll
        for (int rr = 0; rr < 128; rr += 64) {
            const int row = rr + srow;
            *(uint4*)&sA[row * 32 + sk8] = *(const uint4*)&A[(long)(m0 + row) * 512 + k0 + sk8];
            *(uint4*)&sB[row * 32 + sk8] = *(const uint4*)&Bt[(long)(n0 + row) * 512 + k0 + sk8];
        }
        __syncthreads();
        half8 af[4], bf[4];
#pragma unroll
        for (int mi = 0; mi < 4; mi++)
            af[mi] = *(half8*)&sA[(wm * 64 + mi * 16 + lrow) * 32 + quad * 8];
#pragma unroll
        for (int ni = 0; ni < 4; ni++)
            bf[ni] = *(half8*)&sB[(wn * 64 + ni * 16 + lrow) * 32 + quad * 8];
#pragma unroll
        for (int mi = 0; mi < 4; mi++)
#pragma unroll
            for (int ni = 0; ni < 4; ni++)
                acc[mi][ni] = __builtin_amdgcn_mfma_f32_16x16x32_f16(af[mi], bf[ni], acc[mi][ni], 0, 0, 0);
        __syncthreads();
    }
#pragma unroll
    for (int mi = 0; mi < 4; mi++)
#pragma unroll
        for (int ni = 0; ni < 4; ni++)
#pragma unroll
            for (int r = 0; r < 4; r++) {
                int m = m0 + wm * 64 + mi * 16 + quad * 4 + r;
                int n = n0 + wn * 64 + ni * 16 + lrow;
                C[(long)m * NG + n] = (f16)(acc[mi][ni][r] + bias[n]);
            }
}

// ---------------- phase 3: out[b][t][n] = relu(hs @ Wo + bo) (f32 out, row remap) ----------------
__launch_bounds__(256)
__global__ void gemm_hw(const f16* __restrict__ A, const f16* __restrict__ Bt,
                        const float* __restrict__ bias, float* __restrict__ out)
{
    __shared__ f16 sA[128 * 32];
    __shared__ f16 sB[128 * 32];
    const int tid = threadIdx.x;
    const int m0 = blockIdx.y * 128;
    const int n0 = blockIdx.x * 128;
    const int wave = tid >> 6, lane = tid & 63;
    const int wm = wave >> 1, wn = wave & 1;
    const int lrow = lane & 15, quad = lane >> 4;

    float4v acc[4][4];
#pragma unroll
    for (int i = 0; i < 4; i++)
#pragma unroll
        for (int j = 0; j < 4; j++) acc[i][j] = (float4v){0.f, 0.f, 0.f, 0.f};

    const int srow = tid >> 2;
    const int sk8 = (tid & 3) * 8;

    for (int k0 = 0; k0 < 512; k0 += 32) {
#pragma unroll
        for (int rr = 0; rr < 128; rr += 64) {
            const int row = rr + srow;
            *(uint4*)&sA[row * 32 + sk8] = *(const uint4*)&A[(long)(m0 + row) * 512 + k0 + sk8];
            *(uint4*)&sB[row * 32 + sk8] = *(const uint4*)&Bt[(long)(n0 + row) * 512 + k0 + sk8];
        }
        __syncthreads();
        half8 af[4], bf[4];
#pragma unroll
        for (int mi = 0; mi < 4; mi++)
            af[mi] = *(half8*)&sA[(wm * 64 + mi * 16 + lrow) * 32 + quad * 8];
#pragma unroll
        for (int ni = 0; ni < 4; ni++)
            bf[ni] = *(half8*)&sB[(wn * 64 + ni * 16 + lrow) * 32 + quad * 8];
#pragma unroll
        for (int mi = 0; mi < 4; mi++)
#pragma unroll
            for (int ni = 0; ni < 4; ni++)
                acc[mi][ni] = __builtin_amdgcn_mfma_f32_16x16x32_f16(af[mi], bf[ni], acc[mi][ni], 0, 0, 0);
        __syncthreads();
    }
#pragma unroll
    for (int mi = 0; mi < 4; mi++)
#pragma unroll
        for (int ni = 0; ni < 4; ni++)
#pragma unroll
            for (int r = 0; r < 4; r++) {
                int m = m0 + wm * 64 + mi * 16 + quad * 4 + r;   // m = t*B + b
                int n = n0 + wn * 64 + ni * 16 + lrow;
                float v = acc[mi][ni][r] + bias[n];
                v = fmaxf(v, 0.f);
                int t = m >> 5, b = m & 31;
                out[(long)b * (T_ * (long)N_) + (long)t * N_ + n] = v;
            }
}

// ---------------- phase 2: the recurrence (16-batch MFMA, coalesced poll) ----------------
// Same as R4 EXCEPT the poll mapping. R4's thread tid polled slots
// [tid*16, tid*16+16): each poll-load had 64 lanes striding 128B -> 64 cache
// lines per instruction, saturating the L2/atomic path with spin traffic
// (dur 13.5ms, HBM idle). Now thread tid polls slots {i*256 + tid, i=0..15}:
// every load is 64 CONSECUTIVE u64 per wave (512B), ~16x fewer line requests.
// v[i] is then batch i, pair tid -> hbuf write is 16 single-dword LDS writes
// at row i, dword tid ^ ((i&7)<<2) (same XOR the MFMA A-read uses; 2-way
// alias = free). s_sleep(1) only in the retry path (storm guard).
// Everything else (MFMA structure, gates, stores, protocol) identical to R4.
// Protocol safety unchanged: tagged u64 slots, relaxed agent-scope atomics,
// parity double-buffer; producer overwrites a parity-p slot (tag t+2 over t)
// only after observing all tags t+1, which requires every peer to have passed
// the barrier after its tag-t reads.
__launch_bounds__(256, 1)
__global__ void lstm_rec(const f16* __restrict__ Ut,      // [2048 cols][512 rows] f16
                         const f16* __restrict__ xpre,    // [B][T][2048] f16
                         u64* __restrict__ hg64,          // [2][32][256] tagged h pairs
                         unsigned* __restrict__ hs32,     // [T][B][256] u32 (packed f16x2)
                         int unused)
{
    if ((blockIdx.x & 7) >= 2) return;    // dummy blocks for XCD placement
    const int group = blockIdx.x & 7;     // 0 or 1 (16 batches each)
    const int slice = blockIdx.x >> 3;    // 0..7 (64 n-cols each)
    const int n0 = slice * 64;

    const int tid  = threadIdx.x;         // 0..255
    const int g    = tid >> 6;            // wave = gate 0..3
    const int lane = tid & 63;
    const int quad = lane >> 4;           // 0..3
    const int lcol = lane & 15;           // MFMA col (n) / row (batch) index

    __shared__ __align__(16) unsigned hbuf[4096];     // h: [16 b][256 dw], XOR-swizzled
    __shared__ float prelds[4224];                    // [4 g][16 b][66 (64 n + pad)]

    // ---- persistent B-fragments: this wave's gate, 4 n-tiles x 16 ks ----
    half8 bf[4][16];
#pragma unroll
    for (int nt = 0; nt < 4; nt++) {
        const f16* bp = Ut + (long)(g * 512 + n0 + nt * 16 + lcol) * 512 + quad * 8;
#pragma unroll
        for (int ks = 0; ks < 16; ks++)
            bf[nt][ks] = *(const half8*)(bp + ks * 32);
    }

    // zero h_{-1}
#pragma unroll
    for (int i = 0; i < 16; i++) hbuf[tid * 16 + i] = 0u;

    // gate-thread identity: batch b, pair-slot tau; covers np in {tau, tau+16}
    const int b   = tid >> 4;             // 0..15
    const int tau = tid & 15;
    const int bglobal = group * 16 + b;

    // c-state: 4 columns (2 np-pairs x 2 cols)
    float cs00 = 0.f, cs01 = 0.f, cs10 = 0.f, cs11 = 0.f;

    // xpre addressing (u32 = packed pair): idx = t*1024 + g*256 + np
    const unsigned* xq = (const unsigned*)(xpre + (long)bglobal * T_ * NG + n0);
    unsigned xc[8], xn[8];
#pragma unroll
    for (int gg = 0; gg < 4; gg++)
#pragma unroll
        for (int j = 0; j < 2; j++)
            xc[gg * 2 + j] = xq[gg * 256 + tau + j * 16];   // t = 0

    __syncthreads();   // prologue full sync (one-time vmcnt drain is fine)

#pragma unroll 1
    for (int t = 0; t < T_; ++t) {
        // ---- P0: poll h_{t-1}; thread tid polls pair `tid` of all 16 batches
        //      (slot i*256 + tid -> 64 consecutive u64 per wave-load) ----
        if (t > 0) {
            const u64* base = hg64 + (size_t)(t & 1) * 8192 + (size_t)group * 4096 + tid;
            const unsigned tag = (unsigned)t;
            u64 v[16];
#pragma unroll
            for (int i = 0; i < 16; i++)
                v[i] = __hip_atomic_load(base + (size_t)i * 256, __ATOMIC_RELAXED,
                                         __HIP_MEMORY_SCOPE_AGENT);
#pragma unroll
            for (int i = 0; i < 16; i++)
                while ((unsigned)(v[i] >> 32) != tag) {
                    __builtin_amdgcn_s_sleep(1);
                    v[i] = __hip_atomic_load(base + (size_t)i * 256, __ATOMIC_RELAXED,
                                             __HIP_MEMORY_SCOPE_AGENT);
                }
            __builtin_amdgcn_sched_barrier(0);   // keep prefetch below the poll waits

            // xpre prefetch for t+1 (drained by NEXT step's poll, ~1 step away)
            {
                const long tn = (t + 1 < T_) ? (t + 1) : t;
#pragma unroll
                for (int gg = 0; gg < 4; gg++)
#pragma unroll
                    for (int j = 0; j < 2; j++)
                        xn[gg * 2 + j] = xq[tn * 1024 + gg * 256 + tau + j * 16];
            }

            // write h into swizzled hbuf: batch i, dword tid
#pragma unroll
            for (int i = 0; i < 16; i++)
                hbuf[i * 256 + (tid ^ ((i & 7) << 2))] = (unsigned)v[i];
        } else {
            // t=0: hbuf already zero; still prefetch t=1
#pragma unroll
            for (int gg = 0; gg < 4; gg++)
#pragma unroll
                for (int j = 0; j < 2; j++)
                    xn[gg * 2 + j] = xq[1024 + gg * 256 + tau + j * 16];
        }

        asm volatile("s_waitcnt lgkmcnt(0)" ::: "memory");
        __builtin_amdgcn_s_barrier();
        __builtin_amdgcn_sched_barrier(0);

        // ---- P1: MFMA  (A = 16 batches' h, B = U frags) ----
        uint4 av[16];
        {
            const int swb = (lcol & 7) << 2;     // batch = lcol
#pragma unroll
            for (int ks = 0; ks < 16; ks++)
                av[ks] = *(const uint4*)&hbuf[lcol * 256 + (((ks * 16 + quad * 4)) ^ swb)];
        }
        float4v ae[4], ao[4];
#pragma unroll
        for (int nt = 0; nt < 4; nt++) {
            ae[nt] = (float4v){0.f, 0.f, 0.f, 0.f};
            ao[nt] = (float4v){0.f, 0.f, 0.f, 0.f};
        }
#pragma unroll
        for (int ks = 0; ks < 16; ks++) {
            U4H8 a; a.u = av[ks];
            if (ks & 1) {
#pragma unroll
                for (int nt = 0; nt < 4; nt++)
                    ao[nt] = __builtin_amdgcn_mfma_f32_16x16x32_f16(a.h, bf[nt][ks], ao[nt], 0, 0, 0);
            } else {
#pragma unroll
                for (int nt = 0; nt < 4; nt++)
                    ae[nt] = __builtin_amdgcn_mfma_f32_16x16x32_f16(a.h, bf[nt][ks], ae[nt], 0, 0, 0);
            }
        }

        // ---- P2: write pre-acts to prelds: [g][b=quad*4+r][n=nt*16+lcol] ----
#pragma unroll
        for (int nt = 0; nt < 4; nt++) {
            float4v s;
#pragma unroll
            for (int r = 0; r < 4; r++) s[r] = ae[nt][r] + ao[nt][r];
#pragma unroll
            for (int r = 0; r < 4; r++)
                prelds[g * 1056 + (quad * 4 + r) * 66 + nt * 16 + lcol] = s[r];
        }

        asm volatile("s_waitcnt lgkmcnt(0)" ::: "memory");
        __builtin_amdgcn_s_barrier();
        __builtin_amdgcn_sched_barrier(0);

        // ---- P3: gates (all 256 threads; thread = (b, tau); 2 np-pairs) ----
#pragma unroll
        for (int j = 0; j < 2; j++) {
            const int np = tau + j * 16;
            const float* pb = prelds + b * 66 + 2 * np;
            float2 Pi = *(const float2*)(pb);
            float2 Pf = *(const float2*)(pb + 1056);
            float2 Pg = *(const float2*)(pb + 2112);
            float2 Pc = *(const float2*)(pb + 3168);
            U32H2 xi, xf, xg, xcc;
            xi.u = xc[0 * 2 + j]; xf.u = xc[1 * 2 + j];
            xg.u = xc[2 * 2 + j]; xcc.u = xc[3 * 2 + j];

            float gi0 = fast_sigmoid(Pi.x + (float)xi.h[0]);
            float gi1 = fast_sigmoid(Pi.y + (float)xi.h[1]);
            float gf0 = fast_sigmoid(Pf.x + (float)xf.h[0]);
            float gf1 = fast_sigmoid(Pf.y + (float)xf.h[1]);
            float gg0 = fast_sigmoid(Pg.x + (float)xg.h[0]);
            float gg1 = fast_sigmoid(Pg.y + (float)xg.h[1]);
            float ct0 = fast_tanh(Pc.x + (float)xcc.h[0]);
            float ct1 = fast_tanh(Pc.y + (float)xcc.h[1]);

            float c0 = (j == 0) ? cs00 : cs10;
            float c1 = (j == 0) ? cs01 : cs11;
            c0 = gf0 * c0 + gi0 * ct0;
            c1 = gf1 * c1 + gi1 * ct1;
            if (j == 0) { cs00 = c0; cs01 = c1; } else { cs10 = c0; cs11 = c1; }

            float h0 = gg0 * fast_tanh(c0);
            float h1 = gg1 * fast_tanh(c1);

            H16U u0, u1; u0.h = (f16)h0; u1.h = (f16)h1;
            unsigned pk = (unsigned)u0.s | ((unsigned)u1.s << 16);
            u64 pv = ((u64)(unsigned)(t + 1) << 32) | (u64)pk;
            const int pair = slice * 32 + np;
            __hip_atomic_store(hg64 + (size_t)((t + 1) & 1) * 8192 + (size_t)bglobal * 256 + pair,
                               pv, __ATOMIC_RELAXED, __HIP_MEMORY_SCOPE_AGENT);
            // history for gemm_hw (not on critical path)
            hs32[((long)t * B_ + bglobal) * 256 + pair] = pk;
        }

        // rotate xpre pipeline registers
#pragma unroll
        for (int k = 0; k < 8; k++) xc[k] = xn[k];
        // no trailing barrier: next poll + barrier provide ordering
    }
}

// ---------------- launch ----------------
extern "C" void kernel_launch(void* const* d_in, const int* in_sizes, int n_in,
                              void* d_out, int out_size, void* d_ws, size_t ws_size,
                              hipStream_t stream)
{
    const float* x  = (const float*)d_in[0];
    const float* Wi = (const float*)d_in[1];
    const float* Ui = (const float*)d_in[2];
    const float* Wf = (const float*)d_in[3];
    const float* Uf = (const float*)d_in[4];
    const float* Wg = (const float*)d_in[5];
    const float* Ug = (const float*)d_in[6];
    const float* Wc = (const float*)d_in[7];
    const float* Uc = (const float*)d_in[8];
    const float* Wo = (const float*)d_in[9];
    const float* bi = (const float*)d_in[10];
    const float* bf = (const float*)d_in[11];
    const float* bg = (const float*)d_in[12];
    const float* bc = (const float*)d_in[13];
    const float* bo = (const float*)d_in[14];

    char* ws = (char*)d_ws;
    f16*      x16   = (f16*)(ws + 0L);            // 64 MB
    f16*      xpre  = (f16*)(ws + 67108864L);     // 256 MB
    f16*      hs    = (f16*)(ws + 335544320L);    // 64 MB
    f16*      wt    = (f16*)(ws + 402653184L);    // 2 MB
    f16*      ut    = (f16*)(ws + 404750336L);    // 2 MB
    f16*      wot   = (f16*)(ws + 406847488L);    // 0.5 MB
    float*    bias  = (float*)(ws + 407371776L);  // 8 KB
    u64*      hg64  = (u64*)(ws + 407379968L);    // 128 KB tagged h exchange
    // hg64 is re-poisoned to 0xAA each call -> tag 0xAAAAAAAA never matches a
    // real t in [1,2048], so stale data cannot satisfy a poll.

    prep_cast<<<dim3(32768), dim3(256), 0, stream>>>(x, x16);
    prep_w<<<dim3(1024, 10), dim3(256), 0, stream>>>(Wi, Ui, Wf, Uf, Wg, Ug, Wc, Uc, Wo,
                                                     bi, bf, bg, bc, wt, ut, wot, bias);
    gemm_xw<<<dim3(16, 512), dim3(256), 0, stream>>>(x16, wt, bias, xpre);
    lstm_rec<<<dim3(64), dim3(256), 0, stream>>>(ut, xpre, hg64, (unsigned*)hs, 0);
    gemm_hw<<<dim3(4, 512), dim3(256), 0, stream>>>(hs, wot, bo, (float*)d_out);
}

// Round 6
// 8050.986 us; speedup vs baseline: 1.7420x; 1.4418x over previous
//
#include <hip/hip_runtime.h>
#include <stdint.h>

// Problem constants
#define B_ 32
#define T_ 2048
#define D_ 512
#define N_ 512
#define NG 2048   // 4 gates * N

typedef _Float16 f16;
typedef _Float16 half2v __attribute__((ext_vector_type(2)));
typedef _Float16 half8  __attribute__((ext_vector_type(8)));
typedef float    float4v __attribute__((ext_vector_type(4)));
typedef unsigned long long u64;

union U32H2 { unsigned u; half2v h; };
union U4H8  { uint4 u; half8 h; };
union H16U  { f16 h; unsigned short s; };

static __device__ __forceinline__ float fast_sigmoid(float x) {
    return __builtin_amdgcn_rcpf(1.f + __expf(-x));
}
static __device__ __forceinline__ float fast_tanh(float x) {
    // 1 - 2/(1+e^{2x}): correct limits at +/-inf, no clamp needed
    return 1.f - 2.f * __builtin_amdgcn_rcpf(1.f + __expf(2.f * x));
}

// ---------------- prep: cast x (f32) -> f16 ----------------
__global__ void prep_cast(const float* __restrict__ x, f16* __restrict__ x16) {
    long i = ((long)blockIdx.x * 256 + threadIdx.x) * 4;
    float4 v = *(const float4*)(x + i);
    union { f16 h[4]; uint2 u; } pk;
    pk.h[0] = (f16)v.x; pk.h[1] = (f16)v.y; pk.h[2] = (f16)v.z; pk.h[3] = (f16)v.w;
    *(uint2*)(x16 + i) = pk.u;
}

// ---------------- prep: transpose+cast weights, biases ----------------
__global__ void prep_w(const float* __restrict__ Wi, const float* __restrict__ Ui,
                       const float* __restrict__ Wf, const float* __restrict__ Uf,
                       const float* __restrict__ Wg, const float* __restrict__ Ug,
                       const float* __restrict__ Wc, const float* __restrict__ Uc,
                       const float* __restrict__ Wo,
                       const float* __restrict__ bi, const float* __restrict__ bff,
                       const float* __restrict__ bg, const float* __restrict__ bc,
                       f16* __restrict__ wt, f16* __restrict__ ut,
                       f16* __restrict__ wot, float* __restrict__ bias)
{
    const int y = blockIdx.y;
    const int e = blockIdx.x * 256 + threadIdx.x;   // 0..262143
    if (y < 4) {
        const float* src = (y == 0) ? Wi : (y == 1) ? Wf : (y == 2) ? Wg : Wc;
        int col = e >> 9, d = e & 511;
        wt[(long)y * 512 * 512 + e] = (f16)src[(long)d * 512 + col];   // wt[(g*512+col)][d]
    } else if (y < 8) {
        const float* src = (y == 4) ? Ui : (y == 5) ? Uf : (y == 6) ? Ug : Uc;
        int col = e >> 9, d = e & 511;
        ut[(long)(y - 4) * 512 * 512 + e] = (f16)src[(long)d * 512 + col];
    } else if (y == 8) {
        int col = e >> 9, d = e & 511;
        wot[e] = (f16)Wo[(long)d * 512 + col];
    } else {
        if (e < 2048) {
            const float* bsrc = (e < 512) ? bi : (e < 1024) ? bff : (e < 1536) ? bg : bc;
            bias[e] = bsrc[e & 511];
        }
    }
}

// ---------------- phase 1: xpre[b][t][2048] = x @ [Wi|Wf|Wg|Wc] + bias (f16 out) ----------------
__launch_bounds__(256)
__global__ void gemm_xw(const f16* __restrict__ A, const f16* __restrict__ Bt,
                        const float* __restrict__ bias, f16* __restrict__ C)
{
    __shared__ f16 sA[128 * 32];
    __shared__ f16 sB[128 * 32];
    const int tid = threadIdx.x;
    const int m0 = blockIdx.y * 128;
    const int n0 = blockIdx.x * 128;
    const int wave = tid >> 6, lane = tid & 63;
    const int wm = wave >> 1, wn = wave & 1;
    const int lrow = lane & 15, quad = lane >> 4;

    float4v acc[4][4];
#pragma unroll
    for (int i = 0; i < 4; i++)
#pragma unroll
        for (int j = 0; j < 4; j++) acc[i][j] = (float4v){0.f, 0.f, 0.f, 0.f};

    const int srow = tid >> 2;        // 0..63
    const int sk8 = (tid & 3) * 8;    // 0,8,16,24

    for (int k0 = 0; k0 < 512; k0 += 32) {
#pragma unroll
        for (int rr = 0; rr < 128; rr += 64) {
            const int row = rr + srow;
            *(uint4*)&sA[row * 32 + sk8] = *(const uint4*)&A[(long)(m0 + row) * 512 + k0 + sk8];
            *(uint4*)&sB[row * 32 + sk8] = *(const uint4*)&Bt[(long)(n0 + row) * 512 + k0 + sk8];
        }
        __syncthreads();
        half8 af[4], bf[4];
#pragma unroll
        for (int mi = 0; mi < 4; mi++)
            af[mi] = *(half8*)&sA[(wm * 64 + mi * 16 + lrow) * 32 + quad * 8];
#pragma unroll
        for (int ni = 0; ni < 4; ni++)
            bf[ni] = *(half8*)&sB[(wn * 64 + ni * 16 + lrow) * 32 + quad * 8];
#pragma unroll
        for (int mi = 0; mi < 4; mi++)
#pragma unroll
            for (int ni = 0; ni < 4; ni++)
                acc[mi][ni] = __builtin_amdgcn_mfma_f32_16x16x32_f16(af[mi], bf[ni], acc[mi][ni], 0, 0, 0);
        __syncthreads();
    }
#pragma unroll
    for (int mi = 0; mi < 4; mi++)
#pragma unroll
        for (int ni = 0; ni < 4; ni++)
#pragma unroll
            for (int r = 0; r < 4; r++) {
                int m = m0 + wm * 64 + mi * 16 + quad * 4 + r;
                int n = n0 + wn * 64 + ni * 16 + lrow;
                C[(long)m * NG + n] = (f16)(acc[mi][ni][r] + bias[n]);
            }
}

// ---------------- phase 3: out[b][t][n] = relu(hs @ Wo + bo) (f32 out, row remap) ----------------
__launch_bounds__(256)
__global__ void gemm_hw(const f16* __restrict__ A, const f16* __restrict__ Bt,
                        const float* __restrict__ bias, float* __restrict__ out)
{
    __shared__ f16 sA[128 * 32];
    __shared__ f16 sB[128 * 32];
    const int tid = threadIdx.x;
    const int m0 = blockIdx.y * 128;
    const int n0 = blockIdx.x * 128;
    const int wave = tid >> 6, lane = tid & 63;
    const int wm = wave >> 1, wn = wave & 1;
    const int lrow = lane & 15, quad = lane >> 4;

    float4v acc[4][4];
#pragma unroll
    for (int i = 0; i < 4; i++)
#pragma unroll
        for (int j = 0; j < 4; j++) acc[i][j] = (float4v){0.f, 0.f, 0.f, 0.f};

    const int srow = tid >> 2;
    const int sk8 = (tid & 3) * 8;

    for (int k0 = 0; k0 < 512; k0 += 32) {
#pragma unroll
        for (int rr = 0; rr < 128; rr += 64) {
            const int row = rr + srow;
            *(uint4*)&sA[row * 32 + sk8] = *(const uint4*)&A[(long)(m0 + row) * 512 + k0 + sk8];
            *(uint4*)&sB[row * 32 + sk8] = *(const uint4*)&Bt[(long)(n0 + row) * 512 + k0 + sk8];
        }
        __syncthreads();
        half8 af[4], bf[4];
#pragma unroll
        for (int mi = 0; mi < 4; mi++)
            af[mi] = *(half8*)&sA[(wm * 64 + mi * 16 + lrow) * 32 + quad * 8];
#pragma unroll
        for (int ni = 0; ni < 4; ni++)
            bf[ni] = *(half8*)&sB[(wn * 64 + ni * 16 + lrow) * 32 + quad * 8];
#pragma unroll
        for (int mi = 0; mi < 4; mi++)
#pragma unroll
            for (int ni = 0; ni < 4; ni++)
                acc[mi][ni] = __builtin_amdgcn_mfma_f32_16x16x32_f16(af[mi], bf[ni], acc[mi][ni], 0, 0, 0);
        __syncthreads();
    }
#pragma unroll
    for (int mi = 0; mi < 4; mi++)
#pragma unroll
        for (int ni = 0; ni < 4; ni++)
#pragma unroll
            for (int r = 0; r < 4; r++) {
                int m = m0 + wm * 64 + mi * 16 + quad * 4 + r;   // m = t*B + b
                int n = n0 + wn * 64 + ni * 16 + lrow;
                float v = acc[mi][ni][r] + bias[n];
                v = fmaxf(v, 0.f);
                int t = m >> 5, b = m & 31;
                out[(long)b * (T_ * (long)N_) + (long)t * N_ + n] = v;
            }
}

// ---------------- phase 2: the recurrence (16-batch MFMA, batched-retry poll) ----------------
// Identical to R5 EXCEPT the poll retry structure. R5 resolved stale slots
// with 16 SERIAL while-loops: when the consumer arrives early (the normal
// case), all 16 initial loads are stale and each slot then costs a dependent
// ~300-500cy L2 round-trip + 64cy s_sleep, SERIALLY (~5-8k cy/step). Now:
// check all 16 -> if any stale (wave-uniform __all), sleep once and re-issue
// ALL stale loads in one pipelined round -> re-check. Each round costs ~1 L2
// latency regardless of stale count; steady state needs 1-2 rounds.
// Everything else (slot mapping, MFMA structure, gates, stores, protocol)
// byte-identical to R5. Protocol safety unchanged: tagged u64 slots, relaxed
// agent-scope atomics, parity double-buffer; producer overwrites a parity-p
// slot (tag t+2 over t) only after observing all tags t+1, which requires
// every peer to have passed the barrier after its tag-t reads.
__launch_bounds__(256, 1)
__global__ void lstm_rec(const f16* __restrict__ Ut,      // [2048 cols][512 rows] f16
                         const f16* __restrict__ xpre,    // [B][T][2048] f16
                         u64* __restrict__ hg64,          // [2][32][256] tagged h pairs
                         unsigned* __restrict__ hs32,     // [T][B][256] u32 (packed f16x2)
                         int unused)
{
    if ((blockIdx.x & 7) >= 2) return;    // dummy blocks for XCD placement
    const int group = blockIdx.x & 7;     // 0 or 1 (16 batches each)
    const int slice = blockIdx.x >> 3;    // 0..7 (64 n-cols each)
    const int n0 = slice * 64;

    const int tid  = threadIdx.x;         // 0..255
    const int g    = tid >> 6;            // wave = gate 0..3
    const int lane = tid & 63;
    const int quad = lane >> 4;           // 0..3
    const int lcol = lane & 15;           // MFMA col (n) / row (batch) index

    __shared__ __align__(16) unsigned hbuf[4096];     // h: [16 b][256 dw], XOR-swizzled
    __shared__ float prelds[4224];                    // [4 g][16 b][66 (64 n + pad)]

    // ---- persistent B-fragments: this wave's gate, 4 n-tiles x 16 ks ----
    half8 bf[4][16];
#pragma unroll
    for (int nt = 0; nt < 4; nt++) {
        const f16* bp = Ut + (long)(g * 512 + n0 + nt * 16 + lcol) * 512 + quad * 8;
#pragma unroll
        for (int ks = 0; ks < 16; ks++)
            bf[nt][ks] = *(const half8*)(bp + ks * 32);
    }

    // zero h_{-1}
#pragma unroll
    for (int i = 0; i < 16; i++) hbuf[tid * 16 + i] = 0u;

    // gate-thread identity: batch b, pair-slot tau; covers np in {tau, tau+16}
    const int b   = tid >> 4;             // 0..15
    const int tau = tid & 15;
    const int bglobal = group * 16 + b;

    // c-state: 4 columns (2 np-pairs x 2 cols)
    float cs00 = 0.f, cs01 = 0.f, cs10 = 0.f, cs11 = 0.f;

    // xpre addressing (u32 = packed pair): idx = t*1024 + g*256 + np
    const unsigned* xq = (const unsigned*)(xpre + (long)bglobal * T_ * NG + n0);
    unsigned xc[8], xn[8];
#pragma unroll
    for (int gg = 0; gg < 4; gg++)
#pragma unroll
        for (int j = 0; j < 2; j++)
            xc[gg * 2 + j] = xq[gg * 256 + tau + j * 16];   // t = 0

    __syncthreads();   // prologue full sync (one-time vmcnt drain is fine)

#pragma unroll 1
    for (int t = 0; t < T_; ++t) {
        // ---- P0: poll h_{t-1}; thread tid polls pair `tid` of all 16 batches
        //      (slot i*256 + tid -> 64 consecutive u64 per wave-load).
        //      Batched retry: re-issue all stale loads per round, pipelined. ----
        if (t > 0) {
            const u64* base = hg64 + (size_t)(t & 1) * 8192 + (size_t)group * 4096 + tid;
            const unsigned tag = (unsigned)t;
            u64 v[16];
#pragma unroll
            for (int i = 0; i < 16; i++)
                v[i] = __hip_atomic_load(base + (size_t)i * 256, __ATOMIC_RELAXED,
                                         __HIP_MEMORY_SCOPE_AGENT);
            while (true) {
                int ok = 1;
#pragma unroll
                for (int i = 0; i < 16; i++)
                    ok &= ((unsigned)(v[i] >> 32) == tag) ? 1 : 0;
                if (__all(ok)) break;
                __builtin_amdgcn_s_sleep(1);
#pragma unroll
                for (int i = 0; i < 16; i++)
                    if ((unsigned)(v[i] >> 32) != tag)
                        v[i] = __hip_atomic_load(base + (size_t)i * 256, __ATOMIC_RELAXED,
                                                 __HIP_MEMORY_SCOPE_AGENT);
            }
            __builtin_amdgcn_sched_barrier(0);   // keep prefetch below the poll waits

            // xpre prefetch for t+1 (drained by NEXT step's poll, ~1 step away)
            {
                const long tn = (t + 1 < T_) ? (t + 1) : t;
#pragma unroll
                for (int gg = 0; gg < 4; gg++)
#pragma unroll
                    for (int j = 0; j < 2; j++)
                        xn[gg * 2 + j] = xq[tn * 1024 + gg * 256 + tau + j * 16];
            }

            // write h into swizzled hbuf: batch i, dword tid
#pragma unroll
            for (int i = 0; i < 16; i++)
                hbuf[i * 256 + (tid ^ ((i & 7) << 2))] = (unsigned)v[i];
        } else {
            // t=0: hbuf already zero; still prefetch t=1
#pragma unroll
            for (int gg = 0; gg < 4; gg++)
#pragma unroll
                for (int j = 0; j < 2; j++)
                    xn[gg * 2 + j] = xq[1024 + gg * 256 + tau + j * 16];
        }

        asm volatile("s_waitcnt lgkmcnt(0)" ::: "memory");
        __builtin_amdgcn_s_barrier();
        __builtin_amdgcn_sched_barrier(0);

        // ---- P1: MFMA  (A = 16 batches' h, B = U frags) ----
        uint4 av[16];
        {
            const int swb = (lcol & 7) << 2;     // batch = lcol
#pragma unroll
            for (int ks = 0; ks < 16; ks++)
                av[ks] = *(const uint4*)&hbuf[lcol * 256 + (((ks * 16 + quad * 4)) ^ swb)];
        }
        float4v ae[4], ao[4];
#pragma unroll
        for (int nt = 0; nt < 4; nt++) {
            ae[nt] = (float4v){0.f, 0.f, 0.f, 0.f};
            ao[nt] = (float4v){0.f, 0.f, 0.f, 0.f};
        }
#pragma unroll
        for (int ks = 0; ks < 16; ks++) {
            U4H8 a; a.u = av[ks];
            if (ks & 1) {
#pragma unroll
                for (int nt = 0; nt < 4; nt++)
                    ao[nt] = __builtin_amdgcn_mfma_f32_16x16x32_f16(a.h, bf[nt][ks], ao[nt], 0, 0, 0);
            } else {
#pragma unroll
                for (int nt = 0; nt < 4; nt++)
                    ae[nt] = __builtin_amdgcn_mfma_f32_16x16x32_f16(a.h, bf[nt][ks], ae[nt], 0, 0, 0);
            }
        }

        // ---- P2: write pre-acts to prelds: [g][b=quad*4+r][n=nt*16+lcol] ----
#pragma unroll
        for (int nt = 0; nt < 4; nt++) {
            float4v s;
#pragma unroll
            for (int r = 0; r < 4; r++) s[r] = ae[nt][r] + ao[nt][r];
#pragma unroll
            for (int r = 0; r < 4; r++)
                prelds[g * 1056 + (quad * 4 + r) * 66 + nt * 16 + lcol] = s[r];
        }

        asm volatile("s_waitcnt lgkmcnt(0)" ::: "memory");
        __builtin_amdgcn_s_barrier();
        __builtin_amdgcn_sched_barrier(0);

        // ---- P3: gates (all 256 threads; thread = (b, tau); 2 np-pairs) ----
#pragma unroll
        for (int j = 0; j < 2; j++) {
            const int np = tau + j * 16;
            const float* pb = prelds + b * 66 + 2 * np;
            float2 Pi = *(const float2*)(pb);
            float2 Pf = *(const float2*)(pb + 1056);
            float2 Pg = *(const float2*)(pb + 2112);
            float2 Pc = *(const float2*)(pb + 3168);
            U32H2 xi, xf, xg, xcc;
            xi.u = xc[0 * 2 + j]; xf.u = xc[1 * 2 + j];
            xg.u = xc[2 * 2 + j]; xcc.u = xc[3 * 2 + j];

            float gi0 = fast_sigmoid(Pi.x + (float)xi.h[0]);
            float gi1 = fast_sigmoid(Pi.y + (float)xi.h[1]);
            float gf0 = fast_sigmoid(Pf.x + (float)xf.h[0]);
            float gf1 = fast_sigmoid(Pf.y + (float)xf.h[1]);
            float gg0 = fast_sigmoid(Pg.x + (float)xg.h[0]);
            float gg1 = fast_sigmoid(Pg.y + (float)xg.h[1]);
            float ct0 = fast_tanh(Pc.x + (float)xcc.h[0]);
            float ct1 = fast_tanh(Pc.y + (float)xcc.h[1]);

            float c0 = (j == 0) ? cs00 : cs10;
            float c1 = (j == 0) ? cs01 : cs11;
            c0 = gf0 * c0 + gi0 * ct0;
            c1 = gf1 * c1 + gi1 * ct1;
            if (j == 0) { cs00 = c0; cs01 = c1; } else { cs10 = c0; cs11 = c1; }

            float h0 = gg0 * fast_tanh(c0);
            float h1 = gg1 * fast_tanh(c1);

            H16U u0, u1; u0.h = (f16)h0; u1.h = (f16)h1;
            unsigned pk = (unsigned)u0.s | ((unsigned)u1.s << 16);
            u64 pv = ((u64)(unsigned)(t + 1) << 32) | (u64)pk;
            const int pair = slice * 32 + np;
            __hip_atomic_store(hg64 + (size_t)((t + 1) & 1) * 8192 + (size_t)bglobal * 256 + pair,
                               pv, __ATOMIC_RELAXED, __HIP_MEMORY_SCOPE_AGENT);
            // history for gemm_hw (not on critical path)
            hs32[((long)t * B_ + bglobal) * 256 + pair] = pk;
        }

        // rotate xpre pipeline registers
#pragma unroll
        for (int k = 0; k < 8; k++) xc[k] = xn[k];
        // no trailing barrier: next poll + barrier provide ordering
    }
}

// ---------------- launch ----------------
extern "C" void kernel_launch(void* const* d_in, const int* in_sizes, int n_in,
                              void* d_out, int out_size, void* d_ws, size_t ws_size,
                              hipStream_t stream)
{
    const float* x  = (const float*)d_in[0];
    const float* Wi = (const float*)d_in[1];
    const float* Ui = (const float*)d_in[2];
    const float* Wf = (const float*)d_in[3];
    const float* Uf = (const float*)d_in[4];
    const float* Wg = (const float*)d_in[5];
    const float* Ug = (const float*)d_in[6];
    const float* Wc = (const float*)d_in[7];
    const float* Uc = (const float*)d_in[8];
    const float* Wo = (const float*)d_in[9];
    const float* bi = (const float*)d_in[10];
    const float* bf = (const float*)d_in[11];
    const float* bg = (const float*)d_in[12];
    const float* bc = (const float*)d_in[13];
    const float* bo = (const float*)d_in[14];

    char* ws = (char*)d_ws;
    f16*      x16   = (f16*)(ws + 0L);            // 64 MB
    f16*      xpre  = (f16*)(ws + 67108864L);     // 256 MB
    f16*      hs    = (f16*)(ws + 335544320L);    // 64 MB
    f16*      wt    = (f16*)(ws + 402653184L);    // 2 MB
    f16*      ut    = (f16*)(ws + 404750336L);    // 2 MB
    f16*      wot   = (f16*)(ws + 406847488L);    // 0.5 MB
    float*    bias  = (float*)(ws + 407371776L);  // 8 KB
    u64*      hg64  = (u64*)(ws + 407379968L);    // 128 KB tagged h exchange
    // hg64 is re-poisoned to 0xAA each call -> tag 0xAAAAAAAA never matches a
    // real t in [1,2048], so stale data cannot satisfy a poll.

    prep_cast<<<dim3(32768), dim3(256), 0, stream>>>(x, x16);
    prep_w<<<dim3(1024, 10), dim3(256), 0, stream>>>(Wi, Ui, Wf, Uf, Wg, Ug, Wc, Uc, Wo,
                                                     bi, bf, bg, bc, wt, ut, wot, bias);
    gemm_xw<<<dim3(16, 512), dim3(256), 0, stream>>>(x16, wt, bias, xpre);
    lstm_rec<<<dim3(64), dim3(256), 0, stream>>>(ut, xpre, hg64, (unsigned*)hs, 0);
    gemm_hw<<<dim3(4, 512), dim3(256), 0, stream>>>(hs, wot, bo, (float*)d_out);
}

// Round 7
// 3703.997 us; speedup vs baseline: 3.7864x; 2.1736x over previous
//
#include <hip/hip_runtime.h>
#include <stdint.h>

// Problem constants
#define B_ 32
#define T_ 2048
#define D_ 512
#define N_ 512
#define NG 2048   // 4 gates * N

typedef _Float16 f16;
typedef _Float16 half2v __attribute__((ext_vector_type(2)));
typedef _Float16 half8  __attribute__((ext_vector_type(8)));
typedef float    float4v __attribute__((ext_vector_type(4)));
typedef unsigned long long u64;

union U32H2 { unsigned u; half2v h; };
union U4H8  { uint4 u; half8 h; };
union H16U  { f16 h; unsigned short s; };

static __device__ __forceinline__ float fast_sigmoid(float x) {
    return __builtin_amdgcn_rcpf(1.f + __expf(-x));
}
static __device__ __forceinline__ float fast_tanh(float x) {
    // 1 - 2/(1+e^{2x}): correct limits at +/-inf, no clamp needed
    return 1.f - 2.f * __builtin_amdgcn_rcpf(1.f + __expf(2.f * x));
}

// ---------------- prep: cast x (f32) -> f16 ----------------
__global__ void prep_cast(const float* __restrict__ x, f16* __restrict__ x16) {
    long i = ((long)blockIdx.x * 256 + threadIdx.x) * 4;
    float4 v = *(const float4*)(x + i);
    union { f16 h[4]; uint2 u; } pk;
    pk.h[0] = (f16)v.x; pk.h[1] = (f16)v.y; pk.h[2] = (f16)v.z; pk.h[3] = (f16)v.w;
    *(uint2*)(x16 + i) = pk.u;
}

// ---------------- prep: transpose+cast weights, biases ----------------
__global__ void prep_w(const float* __restrict__ Wi, const float* __restrict__ Ui,
                       const float* __restrict__ Wf, const float* __restrict__ Uf,
                       const float* __restrict__ Wg, const float* __restrict__ Ug,
                       const float* __restrict__ Wc, const float* __restrict__ Uc,
                       const float* __restrict__ Wo,
                       const float* __restrict__ bi, const float* __restrict__ bff,
                       const float* __restrict__ bg, const float* __restrict__ bc,
                       f16* __restrict__ wt, f16* __restrict__ ut,
                       f16* __restrict__ wot, float* __restrict__ bias)
{
    const int y = blockIdx.y;
    const int e = blockIdx.x * 256 + threadIdx.x;   // 0..262143
    if (y < 4) {
        const float* src = (y == 0) ? Wi : (y == 1) ? Wf : (y == 2) ? Wg : Wc;
        int col = e >> 9, d = e & 511;
        wt[(long)y * 512 * 512 + e] = (f16)src[(long)d * 512 + col];   // wt[(g*512+col)][d]
    } else if (y < 8) {
        const float* src = (y == 4) ? Ui : (y == 5) ? Uf : (y == 6) ? Ug : Uc;
        int col = e >> 9, d = e & 511;
        ut[(long)(y - 4) * 512 * 512 + e] = (f16)src[(long)d * 512 + col];
    } else if (y == 8) {
        int col = e >> 9, d = e & 511;
        wot[e] = (f16)Wo[(long)d * 512 + col];
    } else {
        if (e < 2048) {
            const float* bsrc = (e < 512) ? bi : (e < 1024) ? bff : (e < 1536) ? bg : bc;
            bias[e] = bsrc[e & 511];
        }
    }
}

// ---------------- phase 1: xpre[b][t][2048] = x @ [Wi|Wf|Wg|Wc] + bias (f16 out) ----------------
__launch_bounds__(256)
__global__ void gemm_xw(const f16* __restrict__ A, const f16* __restrict__ Bt,
                        const float* __restrict__ bias, f16* __restrict__ C)
{
    __shared__ f16 sA[128 * 32];
    __shared__ f16 sB[128 * 32];
    const int tid = threadIdx.x;
    const int m0 = blockIdx.y * 128;
    const int n0 = blockIdx.x * 128;
    const int wave = tid >> 6, lane = tid & 63;
    const int wm = wave >> 1, wn = wave & 1;
    const int lrow = lane & 15, quad = lane >> 4;

    float4v acc[4][4];
#pragma unroll
    for (int i = 0; i < 4; i++)
#pragma unroll
        for (int j = 0; j < 4; j++) acc[i][j] = (float4v){0.f, 0.f, 0.f, 0.f};

    const int srow = tid >> 2;        // 0..63
    const int sk8 = (tid & 3) * 8;    // 0,8,16,24

    for (int k0 = 0; k0 < 512; k0 += 32) {
#pragma unroll
        for (int rr = 0; rr < 128; rr += 64) {
            const int row = rr + srow;
            *(uint4*)&sA[row * 32 + sk8] = *(const uint4*)&A[(long)(m0 + row) * 512 + k0 + sk8];
            *(uint4*)&sB[row * 32 + sk8] = *(const uint4*)&Bt[(long)(n0 + row) * 512 + k0 + sk8];
        }
        __syncthreads();
        half8 af[4], bf[4];
#pragma unroll
        for (int mi = 0; mi < 4; mi++)
            af[mi] = *(half8*)&sA[(wm * 64 + mi * 16 + lrow) * 32 + quad * 8];
#pragma unroll
        for (int ni = 0; ni < 4; ni++)
            bf[ni] = *(half8*)&sB[(wn * 64 + ni * 16 + lrow) * 32 + quad * 8];
#pragma unroll
        for (int mi = 0; mi < 4; mi++)
#pragma unroll
            for (int ni = 0; ni < 4; ni++)
                acc[mi][ni] = __builtin_amdgcn_mfma_f32_16x16x32_f16(af[mi], bf[ni], acc[mi][ni], 0, 0, 0);
        __syncthreads();
    }
#pragma unroll
    for (int mi = 0; mi < 4; mi++)
#pragma unroll
        for (int ni = 0; ni < 4; ni++)
#pragma unroll
            for (int r = 0; r < 4; r++) {
                int m = m0 + wm * 64 + mi * 16 + quad * 4 + r;
                int n = n0 + wn * 64 + ni * 16 + lrow;
                C[(long)m * NG + n] = (f16)(acc[mi][ni][r] + bias[n]);
            }
}

// ---------------- phase 3: out[b][t][n] = relu(hs @ Wo + bo) (f32 out, row remap) ----------------
__launch_bounds__(256)
__global__ void gemm_hw(const f16* __restrict__ A, const f16* __restrict__ Bt,
                        const float* __restrict__ bias, float* __restrict__ out)
{
    __shared__ f16 sA[128 * 32];
    __shared__ f16 sB[128 * 32];
    const int tid = threadIdx.x;
    const int m0 = blockIdx.y * 128;
    const int n0 = blockIdx.x * 128;
    const int wave = tid >> 6, lane = tid & 63;
    const int wm = wave >> 1, wn = wave & 1;
    const int lrow = lane & 15, quad = lane >> 4;

    float4v acc[4][4];
#pragma unroll
    for (int i = 0; i < 4; i++)
#pragma unroll
        for (int j = 0; j < 4; j++) acc[i][j] = (float4v){0.f, 0.f, 0.f, 0.f};

    const int srow = tid >> 2;
    const int sk8 = (tid & 3) * 8;

    for (int k0 = 0; k0 < 512; k0 += 32) {
#pragma unroll
        for (int rr = 0; rr < 128; rr += 64) {
            const int row = rr + srow;
            *(uint4*)&sA[row * 32 + sk8] = *(const uint4*)&A[(long)(m0 + row) * 512 + k0 + sk8];
            *(uint4*)&sB[row * 32 + sk8] = *(const uint4*)&Bt[(long)(n0 + row) * 512 + k0 + sk8];
        }
        __syncthreads();
        half8 af[4], bf[4];
#pragma unroll
        for (int mi = 0; mi < 4; mi++)
            af[mi] = *(half8*)&sA[(wm * 64 + mi * 16 + lrow) * 32 + quad * 8];
#pragma unroll
        for (int ni = 0; ni < 4; ni++)
            bf[ni] = *(half8*)&sB[(wn * 64 + ni * 16 + lrow) * 32 + quad * 8];
#pragma unroll
        for (int mi = 0; mi < 4; mi++)
#pragma unroll
            for (int ni = 0; ni < 4; ni++)
                acc[mi][ni] = __builtin_amdgcn_mfma_f32_16x16x32_f16(af[mi], bf[ni], acc[mi][ni], 0, 0, 0);
        __syncthreads();
    }
#pragma unroll
    for (int mi = 0; mi < 4; mi++)
#pragma unroll
        for (int ni = 0; ni < 4; ni++)
#pragma unroll
            for (int r = 0; r < 4; r++) {
                int m = m0 + wm * 64 + mi * 16 + quad * 4 + r;   // m = t*B + b
                int n = n0 + wn * 64 + ni * 16 + lrow;
                float v = acc[mi][ni][r] + bias[n];
                v = fmaxf(v, 0.f);
                int t = m >> 5, b = m & 31;
                out[(long)b * (T_ * (long)N_) + (long)t * N_ + n] = v;
            }
}

// ---------------- phase 2: the recurrence (R2 structure + raw barriers) ----------------
// REVERT to the R2 design (best measured: 3260us): 32 batch-rings x 8 blocks x
// 512 threads (8 waves), per-wave 2 B-frag tiles (128 regs), one-slot-per-
// thread coalesced poll, MFMA h@U with h broadcast, gates on tid<64.
// The R4-R6 16-batch design is abandoned: its poll observes 4096 slots across
// 2 XCD-spanning block groups per step (max of 256 cross-XCD visibility
// latencies) and floored at 7.5ms -- 2.3x worse than R2 -- while the MFMA
// savings bought nothing (matrix pipe was never the bottleneck).
// SINGLE change vs R2: the two in-loop __syncthreads are replaced by raw
// {s_waitcnt lgkmcnt(0); s_barrier; sched_barrier(0)} (pattern validated in
// R3-R6). __syncthreads emits s_waitcnt vmcnt(0), which force-drained the
// xpre prefetch (~issued 300cy earlier) at barrier2 EVERY step -- ~500-700cy
// of exposed HBM latency. With raw barriers the prefetch has a full step
// (~3000cy) before the next poll's own vmcnt wait.
// Comm protocol unchanged (tagged u64, relaxed agent atomics, parity double-
// buffer): producer overwrites slot parity p (tag t+2 over tag t) only after
// its block observed tag t+1 on all polled slots, which -- via the two raw
// barriers that still order in-block execution -- requires every peer block
// to have passed the barrier following its tag-t reads.
__launch_bounds__(512, 2)
__global__ void lstm_rec(const f16* __restrict__ Ut,      // [2048 cols][512 rows] f16
                         const f16* __restrict__ xpre,    // [B][T][2048] f16
                         u64* __restrict__ hg64,          // [2][32][256] tagged h pairs
                         unsigned* __restrict__ hs32,     // [T][B][256] u32 (packed f16x2)
                         int unused)
{
    const int tid = threadIdx.x;
    const int bb = blockIdx.x & 31;   // batch
    const int s  = blockIdx.x >> 5;   // slice 0..7 (blocks of a group 32 apart -> same XCD)
    const int w    = tid >> 6;        // wave 0..7: owns block-cols [32w, 32w+32)
    const int lane = tid & 63;
    const int quad = lane >> 4;
    const int lcol = lane & 15;
    const int g0    = w >> 1;         // gate of this wave's columns
    const int ebase = (w & 1) * 32;   // e-offset within the gate

    __shared__ __align__(16) unsigned hbuf32[256];   // h_{t-1}: 512 f16 packed
    __shared__ float prelds[256];                    // h@U partial per block-col

    // ---- persistent B-fragments: U[:,gcol] for this wave's 32 columns ----
    half8 bf0[16], bf1[16];
    {
        const int e0 = ebase + lcol;
        const int e1 = ebase + 16 + lcol;
        const f16* bp0 = Ut + (long)(g0 * 512 + s * 64 + e0) * 512 + quad * 8;
        const f16* bp1 = Ut + (long)(g0 * 512 + s * 64 + e1) * 512 + quad * 8;
#pragma unroll
        for (int ks = 0; ks < 16; ks++) {
            bf0[ks] = *(const half8*)(bp0 + ks * 32);
            bf1[ks] = *(const half8*)(bp1 + ks * 32);
        }
    }

    if (tid < 256) hbuf32[tid] = 0u;   // h_{-1} = 0
    float cst = 0.f;                   // valid for tid<64: c-state of col s*64+tid
    __syncthreads();                   // prologue: full sync once is fine

    // xpre base for gate lanes: column s*64 + lane, per-gate stride 512 f16
    const f16* xb = xpre + (long)bb * T_ * NG + s * 64 + tid;   // valid use: tid<64

    // preload xpre for t=0 (no poll before it, so no forced drain)
    f16 xc_i = (f16)0, xc_f = (f16)0, xc_g = (f16)0, xc_c = (f16)0;
    if (tid < 64) {
        xc_i = xb[0]; xc_f = xb[512]; xc_g = xb[1024]; xc_c = xb[1536];
    }

    for (int t = 0; t < T_; ++t) {
        // ---- acquire h_{t-1} : poll tagged data words directly ----
        if (t > 0 && tid < 256) {
            const u64* slot = hg64 + (size_t)(t & 1) * 8192 + bb * 256 + tid;
            const unsigned tag = (unsigned)t;
            u64 v;
            while ((unsigned)((v = __hip_atomic_load(slot, __ATOMIC_RELAXED,
                                                     __HIP_MEMORY_SCOPE_AGENT)) >> 32) != tag)
                __builtin_amdgcn_s_sleep(1);
            hbuf32[tid] = (unsigned)v;
        }
        // pin the prefetch below the poll at both IR and MIR level
        asm volatile("" ::: "memory");
        __builtin_amdgcn_sched_barrier(0);

        // ---- issue xpre loads for step t+1 (consumed next iteration's gate
        // phase; with raw barriers below, nothing drains vmcnt before the
        // NEXT step's poll -> ~full step of slack vs ~900cy HBM latency) ----
        f16 xn_i = (f16)0, xn_f = (f16)0, xn_g = (f16)0, xn_c = (f16)0;
        if (t < T_ - 1 && tid < 64) {
            const f16* p = xb + (long)(t + 1) * NG;
            xn_i = p[0]; xn_f = p[512]; xn_g = p[1024]; xn_c = p[1536];
        }

        // ---- barrier 1: publish hbuf (LDS only; NO vmcnt drain) ----
        asm volatile("s_waitcnt lgkmcnt(0)" ::: "memory");
        __builtin_amdgcn_s_barrier();
        __builtin_amdgcn_sched_barrier(0);

        // ---- h @ U via MFMA: A = h broadcast into all 16 rows ----
        float4v a0 = {0.f, 0.f, 0.f, 0.f}, a1 = {0.f, 0.f, 0.f, 0.f};
        float4v a2 = {0.f, 0.f, 0.f, 0.f}, a3 = {0.f, 0.f, 0.f, 0.f};
#pragma unroll
        for (int ks = 0; ks < 16; ks += 2) {
            U4H8 av0, av1;
            av0.u = *(const uint4*)&hbuf32[ks * 16 + quad * 4];
            av1.u = *(const uint4*)&hbuf32[(ks + 1) * 16 + quad * 4];
            a0 = __builtin_amdgcn_mfma_f32_16x16x32_f16(av0.h, bf0[ks],     a0, 0, 0, 0);
            a1 = __builtin_amdgcn_mfma_f32_16x16x32_f16(av0.h, bf1[ks],     a1, 0, 0, 0);
            a2 = __builtin_amdgcn_mfma_f32_16x16x32_f16(av1.h, bf0[ks + 1], a2, 0, 0, 0);
            a3 = __builtin_amdgcn_mfma_f32_16x16x32_f16(av1.h, bf1[ks + 1], a3, 0, 0, 0);
        }
        // All C rows identical; reg0 of lanes 0..31 covers the wave's 32 cols.
        if (lane < 32)
            prelds[w * 32 + lane] = (lane < 16) ? (a0[0] + a2[0]) : (a1[0] + a3[0]);

        // ---- barrier 2: publish prelds (LDS only; NO vmcnt drain) ----
        asm volatile("s_waitcnt lgkmcnt(0)" ::: "memory");
        __builtin_amdgcn_s_barrier();
        __builtin_amdgcn_sched_barrier(0);

        // ---- gates: 64 lanes, one column each ----
        if (tid < 64) {
            float pre_i = prelds[tid]       + (float)xc_i;
            float pre_f = prelds[64 + tid]  + (float)xc_f;
            float pre_g = prelds[128 + tid] + (float)xc_g;
            float pre_c = prelds[192 + tid] + (float)xc_c;
            float gi = fast_sigmoid(pre_i);
            float gf = fast_sigmoid(pre_f);
            float gg = fast_sigmoid(pre_g);
            float ct = fast_tanh(pre_c);
            cst = gf * cst + gi * ct;
            float h = gg * fast_tanh(cst);

            // pack pairs: lane j (<32) collects h from lanes 2j, 2j+1
            H16U cv; cv.h = (f16)h;
            unsigned hx = (unsigned)cv.s;
            unsigned lo = __shfl(hx, 2 * lane);
            unsigned hi = __shfl(hx, 2 * lane + 1);
            if (lane < 32) {
                unsigned pk = lo | (hi << 16);
                u64 pv = ((u64)(unsigned)(t + 1) << 32) | (u64)pk;
                __hip_atomic_store(hg64 + (size_t)((t + 1) & 1) * 8192 + bb * 256 + s * 32 + lane,
                                   pv, __ATOMIC_RELAXED, __HIP_MEMORY_SCOPE_AGENT);
                // history for gemm_hw: normal cached store (not on critical path)
                hs32[((long)t * B_ + bb) * 256 + s * 32 + lane] = pk;
            }
        }
        // rotate xpre pipeline registers
        xc_i = xn_i; xc_f = xn_f; xc_g = xn_g; xc_c = xn_c;
        // no trailing barrier: next iteration's poll + barrier provide ordering
    }
}

// ---------------- launch ----------------
extern "C" void kernel_launch(void* const* d_in, const int* in_sizes, int n_in,
                              void* d_out, int out_size, void* d_ws, size_t ws_size,
                              hipStream_t stream)
{
    const float* x  = (const float*)d_in[0];
    const float* Wi = (const float*)d_in[1];
    const float* Ui = (const float*)d_in[2];
    const float* Wf = (const float*)d_in[3];
    const float* Uf = (const float*)d_in[4];
    const float* Wg = (const float*)d_in[5];
    const float* Ug = (const float*)d_in[6];
    const float* Wc = (const float*)d_in[7];
    const float* Uc = (const float*)d_in[8];
    const float* Wo = (const float*)d_in[9];
    const float* bi = (const float*)d_in[10];
    const float* bf = (const float*)d_in[11];
    const float* bg = (const float*)d_in[12];
    const float* bc = (const float*)d_in[13];
    const float* bo = (const float*)d_in[14];

    char* ws = (char*)d_ws;
    f16*      x16   = (f16*)(ws + 0L);            // 64 MB
    f16*      xpre  = (f16*)(ws + 67108864L);     // 256 MB
    f16*      hs    = (f16*)(ws + 335544320L);    // 64 MB
    f16*      wt    = (f16*)(ws + 402653184L);    // 2 MB
    f16*      ut    = (f16*)(ws + 404750336L);    // 2 MB
    f16*      wot   = (f16*)(ws + 406847488L);    // 0.5 MB
    float*    bias  = (float*)(ws + 407371776L);  // 8 KB
    u64*      hg64  = (u64*)(ws + 407379968L);    // 128 KB tagged h exchange
    // hg64 is re-poisoned to 0xAA each call -> tag 0xAAAAAAAA never matches a
    // real t in [1,2048], so stale data cannot satisfy a poll.

    prep_cast<<<dim3(32768), dim3(256), 0, stream>>>(x, x16);
    prep_w<<<dim3(1024, 10), dim3(256), 0, stream>>>(Wi, Ui, Wf, Uf, Wg, Ug, Wc, Uc, Wo,
                                                     bi, bf, bg, bc, wt, ut, wot, bias);
    gemm_xw<<<dim3(16, 512), dim3(256), 0, stream>>>(x16, wt, bias, xpre);
    lstm_rec<<<dim3(256), dim3(512), 0, stream>>>(ut, xpre, hg64, (unsigned*)hs, 0);
    gemm_hw<<<dim3(4, 512), dim3(256), 0, stream>>>(hs, wot, bo, (float*)d_out);
}